// Round 4
// baseline (294.909 us; speedup 1.0000x reference)
//
#include <hip/hip_runtime.h>

#define EPSV 1e-5f

// problem sizes
#define NB   8
#define CC   128
#define HH   56
#define WW   56
#define HW   3136      // 56*56
#define NHW  25088     // 8*3136
#define GG   8

// workspace offsets (in floats) — total 13247584 floats ~= 53 MB
#define OFF_QKV      0            // [256][NHW]  (o-major; o: 0-63 q, 64-127 k, 128-255 v)
#define OFF_SV       6422528      // [128][NHW]  (ch-major, ch = g*16+c)
#define OFF_SVE      9633792      // [128][NHW]
#define OFF_QRB      12845056     // [b][g][i][w] = [8][8][56][56]
#define OFF_KRB      13045760     // [b][g][j][w]
#define OFF_QKVSC    13246464     // [256] scale
#define OFF_QKVSH    13246720     // [256] shift
#define OFF_ACCUM    13246976     // [48]: qr_s[8], qr_s2[8], kr_s[8], kr_s2[8], qk_s[8], qk_s2[8]
#define OFF_BNPAR    13247024     // [48]: qr_sc[8], qr_sh[8], kr_sc[8], kr_sh[8], qk_sc[8], qk_sh[8]
#define OFF_BNPAR2   13247072     // [512]: sv_sc[128], sv_sh[128], sve_sc[128], sve_sh[128]
#define WS_FLOATS    13247584

// ---------------------------------------------------------------------------
// K1: QKV 1x1-conv GEMM. out[o][p] = sum_k W[o][k] * x[b][k][s], p = b*HW + s.
// C-tile 128o x 64p per block, 256 threads, each thread 8o x 4p registers.
// ---------------------------------------------------------------------------
__global__ __launch_bounds__(256) void k1_qkv(
    const float* __restrict__ x, const float* __restrict__ wq,
    const float* __restrict__ wk, const float* __restrict__ wv,
    float* __restrict__ qkv) {
  __shared__ float Wc[32][132];   // [k][o_local], padded row (528B = 33*16, float4-aligned)
  __shared__ float Xc[32][64];    // [k][p_local]
  const int p0 = blockIdx.x * 64;
  const int o0 = blockIdx.y * 128;
  const int tid = threadIdx.x;
  const int io = tid & 15, ip = tid >> 4;
  const int bb = p0 / HW;
  const int s0 = p0 - bb * HW;    // 64 | 3136, tile never crosses b

  float acc[8][4];
#pragma unroll
  for (int r = 0; r < 8; ++r)
#pragma unroll
    for (int s = 0; s < 4; ++s) acc[r][s] = 0.f;

  for (int kc = 0; kc < 128; kc += 32) {
    if (kc) __syncthreads();
    // stage W chunk transposed: Wc[k][o]
#pragma unroll
    for (int r = 0; r < 4; ++r) {
      int f = tid + 256 * r;            // 1024 float4 slots
      int ol = f >> 3;
      int kq = (f & 7) * 4;
      int o = o0 + ol;
      const float* wsrc = (o < 64) ? (wq + (size_t)o * 128)
                        : (o < 128) ? (wk + (size_t)(o - 64) * 128)
                                    : (wv + (size_t)(o - 128) * 128);
      float4 w4 = *(const float4*)(wsrc + kc + kq);
      Wc[kq + 0][ol] = w4.x; Wc[kq + 1][ol] = w4.y;
      Wc[kq + 2][ol] = w4.z; Wc[kq + 3][ol] = w4.w;
    }
    // stage X chunk: Xc[k][p]
#pragma unroll
    for (int r = 0; r < 2; ++r) {
      int f = tid + 256 * r;            // 512 float4 slots
      int k = f >> 4;
      int pq = (f & 15) * 4;
      float4 x4 = *(const float4*)(x + (size_t)(bb * 128 + kc + k) * HW + s0 + pq);
      *(float4*)&Xc[k][pq] = x4;
    }
    __syncthreads();
#pragma unroll
    for (int k = 0; k < 32; ++k) {
      float4 xv = *(const float4*)&Xc[k][ip * 4];
      float4 wa = *(const float4*)&Wc[k][io * 8];
      float4 wb = *(const float4*)&Wc[k][io * 8 + 4];
      float wr[8] = {wa.x, wa.y, wa.z, wa.w, wb.x, wb.y, wb.z, wb.w};
      float xr[4] = {xv.x, xv.y, xv.z, xv.w};
#pragma unroll
      for (int r = 0; r < 8; ++r)
#pragma unroll
        for (int s = 0; s < 4; ++s)
          acc[r][s] = fmaf(wr[r], xr[s], acc[r][s]);
    }
  }
#pragma unroll
  for (int r = 0; r < 8; ++r) {
    float4 o4 = make_float4(acc[r][0], acc[r][1], acc[r][2], acc[r][3]);
    *(float4*)(qkv + (size_t)(o0 + io * 8 + r) * NHW + p0 + ip * 4) = o4;
  }
}

// ---------------------------------------------------------------------------
// K2: per-channel BN stats for q/k/v -> scale/shift. One block per channel.
// ---------------------------------------------------------------------------
__global__ __launch_bounds__(256) void k2_stats(
    const float* __restrict__ qkv,
    const float* __restrict__ g_q, const float* __restrict__ b_q,
    const float* __restrict__ g_k, const float* __restrict__ b_k,
    const float* __restrict__ g_v, const float* __restrict__ b_v,
    float* __restrict__ sc_out, float* __restrict__ sh_out) {
  const int o = blockIdx.x;
  const float4* p = (const float4*)(qkv + (size_t)o * NHW);
  float s = 0.f, s2 = 0.f;
  for (int f = threadIdx.x; f < NHW / 4; f += 256) {
    float4 v = p[f];
    s  += v.x + v.y + v.z + v.w;
    s2 += v.x * v.x + v.y * v.y + v.z * v.z + v.w * v.w;
  }
#pragma unroll
  for (int off = 32; off > 0; off >>= 1) {
    s  += __shfl_down(s, off);
    s2 += __shfl_down(s2, off);
  }
  __shared__ float ls[8];
  int wv_ = threadIdx.x >> 6, ln = threadIdx.x & 63;
  if (ln == 0) { ls[wv_] = s; ls[4 + wv_] = s2; }
  __syncthreads();
  if (threadIdx.x == 0) {
    s  = ls[0] + ls[1] + ls[2] + ls[3];
    s2 = ls[4] + ls[5] + ls[6] + ls[7];
    float mean = s / (float)NHW;
    float var  = s2 / (float)NHW - mean * mean;
    float g, b;
    if (o < 64)       { g = g_q[o];       b = b_q[o]; }
    else if (o < 128) { g = g_k[o - 64];  b = b_k[o - 64]; }
    else              { g = g_v[o - 128]; b = b_v[o - 128]; }
    float sc = g * rsqrtf(var + EPSV);
    sc_out[o] = sc;
    sh_out[o] = b - mean * sc;
  }
}

// ---------------------------------------------------------------------------
// K3: qr/kr bases (raw, pre-BN) + qk sum/sumsq per group (recomputes S).
// Block = (b, g, 4-w tile); threads (i, wl) with tid<224 active.
// qr is broadcast along j in the reference, so stats over N*H*W are exact.
// ---------------------------------------------------------------------------
__global__ __launch_bounds__(256) void k3_scores(
    const float* __restrict__ qkv,
    const float* __restrict__ qsc, const float* __restrict__ qsh,
    const float* __restrict__ q_rel, const float* __restrict__ k_rel,
    float* __restrict__ qrb, float* __restrict__ krb,
    float* __restrict__ accum) {
  __shared__ float qn[8][4][56];   // [c][wl][i]
  __shared__ float kn[8][4][56];
  __shared__ float red[4][6];
  const int w0 = blockIdx.x * 4, g = blockIdx.y, b = blockIdx.z;
  const int tid = threadIdx.x;

  for (int f = tid; f < 896; f += 256) {
    int isK = f >= 448;
    int idx = f - 448 * isK;
    int c = idx / 56, i = idx - c * 56;
    int o = g * 8 + c + 64 * isK;
    float4 v = *(const float4*)(qkv + (size_t)o * NHW + b * HW + i * 56 + w0);
    float sc = qsc[o], sh = qsh[o];
    float* dst = isK ? &kn[c][0][i] : &qn[c][0][i];
    dst[0]   = fmaf(v.x, sc, sh);
    dst[56]  = fmaf(v.y, sc, sh);
    dst[112] = fmaf(v.z, sc, sh);
    dst[168] = fmaf(v.w, sc, sh);
  }
  __syncthreads();

  float vqr = 0.f, vqr2 = 0.f, vkr = 0.f, vkr2 = 0.f, vqk = 0.f, vqk2 = 0.f;
  if (tid < 224) {
    const int i = tid % 56, wl = tid / 56;
    float qreg[8];
#pragma unroll
    for (int c = 0; c < 8; ++c) qreg[c] = qn[c][wl][i];
    float qrv = 0.f, krv = 0.f;
#pragma unroll
    for (int c = 0; c < 8; ++c) {
      qrv = fmaf(qreg[c], q_rel[c * 56 + i], qrv);
      krv = fmaf(kn[c][wl][i], k_rel[c * 56 + i], krv);
    }
    size_t bo = ((size_t)(b * 8 + g) * 56 + i) * 56 + w0 + wl;
    qrb[bo] = qrv;
    krb[bo] = krv;
    vqr = qrv; vqr2 = qrv * qrv; vkr = krv; vkr2 = krv * krv;
#pragma unroll
    for (int jq = 0; jq < 14; ++jq) {
      float s0 = 0.f, s1 = 0.f, s2 = 0.f, s3 = 0.f;
#pragma unroll
      for (int c = 0; c < 8; ++c) {
        const float* kp = &kn[c][wl][jq * 4];
        float qc = qreg[c];
        s0 = fmaf(qc, kp[0], s0); s1 = fmaf(qc, kp[1], s1);
        s2 = fmaf(qc, kp[2], s2); s3 = fmaf(qc, kp[3], s3);
      }
      vqk  += s0 + s1 + s2 + s3;
      vqk2 += s0 * s0 + s1 * s1 + s2 * s2 + s3 * s3;
    }
  }
  float vals[6] = {vqr, vqr2, vkr, vkr2, vqk, vqk2};
#pragma unroll
  for (int u = 0; u < 6; ++u)
#pragma unroll
    for (int off = 32; off > 0; off >>= 1) vals[u] += __shfl_down(vals[u], off);
  int wv_ = tid >> 6, ln = tid & 63;
  if (ln == 0)
#pragma unroll
    for (int u = 0; u < 6; ++u) red[wv_][u] = vals[u];
  __syncthreads();
  if (tid == 0) {
#pragma unroll
    for (int u = 0; u < 6; ++u)
      atomicAdd(&accum[u * 8 + g], red[0][u] + red[1][u] + red[2][u] + red[3][u]);
  }
}

// ---------------------------------------------------------------------------
// K4: fold accumulated stats into per-group scale/shift for qr, kr, qk.
// ---------------------------------------------------------------------------
__global__ void k4_bn(
    const float* __restrict__ accum,
    const float* __restrict__ g_qr, const float* __restrict__ b_qr,
    const float* __restrict__ g_kr, const float* __restrict__ b_kr,
    const float* __restrict__ g_qk, const float* __restrict__ b_qk,
    float* __restrict__ bnpar) {
  int g = threadIdx.x;
  if (g >= 8) return;
  const float inv1 = 1.f / 25088.f;      // qr/kr count (N*H*W)
  const float inv2 = 1.f / 1404928.f;    // qk count (N*H*H*W)
  float m, v, sc;
  m = accum[g] * inv1;      v = accum[8 + g]  * inv1 - m * m;
  sc = g_qr[g] * rsqrtf(v + EPSV); bnpar[g]      = sc; bnpar[8 + g]  = b_qr[g] - m * sc;
  m = accum[16 + g] * inv1; v = accum[24 + g] * inv1 - m * m;
  sc = g_kr[g] * rsqrtf(v + EPSV); bnpar[16 + g] = sc; bnpar[24 + g] = b_kr[g] - m * sc;
  m = accum[32 + g] * inv2; v = accum[40 + g] * inv2 - m * m;
  sc = g_qk[g] * rsqrtf(v + EPSV); bnpar[32 + g] = sc; bnpar[40 + g] = b_qk[g] - m * sc;
}

// ---------------------------------------------------------------------------
// K5: attention. Block = (b, g, 4-w tile). Thread (i, wl) owns one softmax
// row entirely in registers; LDS reads in the inner loops are lane-invariant
// broadcasts (address depends on wl/c/j only). Writes raw sv and sve.
// ---------------------------------------------------------------------------
__global__ __launch_bounds__(256) void k5_attn(
    const float* __restrict__ qkv,
    const float* __restrict__ qsc, const float* __restrict__ qsh,
    const float* __restrict__ qrb, const float* __restrict__ krb,
    const float* __restrict__ bnpar, const float* __restrict__ v_rel,
    float* __restrict__ sv_ws, float* __restrict__ sve_ws) {
  __shared__ float qn[8][4][56];    // [c][wl][i]
  __shared__ float kn[8][4][56];
  __shared__ float vn[16][4][56];
  __shared__ float qrn[4][56];
  __shared__ float krn[4][56];
  __shared__ float vr[16][56];
  const int w0 = blockIdx.x * 4, g = blockIdx.y, b = blockIdx.z;
  const int tid = threadIdx.x;

  for (int f = tid; f < 1792; f += 256) {
    int c, i, o; float* dst;
    if (f < 448)      { c = f / 56;                 i = f % 56; o = g * 8 + c;         dst = &qn[c][0][i]; }
    else if (f < 896) { int e = f - 448; c = e / 56; i = e % 56; o = 64 + g * 8 + c;   dst = &kn[c][0][i]; }
    else              { int e = f - 896; c = e / 56; i = e % 56; o = 128 + g * 16 + c; dst = &vn[c][0][i]; }
    float4 v = *(const float4*)(qkv + (size_t)o * NHW + b * HW + i * 56 + w0);
    float sc = qsc[o], sh = qsh[o];
    dst[0]   = fmaf(v.x, sc, sh);
    dst[56]  = fmaf(v.y, sc, sh);
    dst[112] = fmaf(v.z, sc, sh);
    dst[168] = fmaf(v.w, sc, sh);
  }
  {
    float qr_sc = bnpar[g],      qr_sh = bnpar[8 + g];
    float kr_sc = bnpar[16 + g], kr_sh = bnpar[24 + g];
    if (tid < 224) {
      int i = tid % 56, wl = tid / 56;
      size_t bo = ((size_t)(b * 8 + g) * 56 + i) * 56 + w0 + wl;
      qrn[wl][i] = fmaf(qrb[bo], qr_sc, qr_sh);
      krn[wl][i] = fmaf(krb[bo], kr_sc, kr_sh);
    }
  }
  for (int f = tid; f < 896; f += 256) ((float*)vr)[f] = v_rel[f];
  __syncthreads();

  if (tid < 224) {
    const int i = tid % 56, wl = tid / 56;
    float qreg[8];
#pragma unroll
    for (int c = 0; c < 8; ++c) qreg[c] = qn[c][wl][i];
    const float qksc = bnpar[32 + g];
    const float addi = bnpar[40 + g] + qrn[wl][i];

    float srow[56];
    float mx = -3.402823466e38f;
#pragma unroll
    for (int jq = 0; jq < 14; ++jq) {
      float s0 = 0.f, s1 = 0.f, s2 = 0.f, s3 = 0.f;
#pragma unroll
      for (int c = 0; c < 8; ++c) {
        const float* kp = &kn[c][wl][jq * 4];
        float qc = qreg[c];
        s0 = fmaf(qc, kp[0], s0); s1 = fmaf(qc, kp[1], s1);
        s2 = fmaf(qc, kp[2], s2); s3 = fmaf(qc, kp[3], s3);
      }
      const float* krp = &krn[wl][jq * 4];
      s0 = fmaf(qksc, s0, addi + krp[0]);
      s1 = fmaf(qksc, s1, addi + krp[1]);
      s2 = fmaf(qksc, s2, addi + krp[2]);
      s3 = fmaf(qksc, s3, addi + krp[3]);
      srow[jq * 4 + 0] = s0; srow[jq * 4 + 1] = s1;
      srow[jq * 4 + 2] = s2; srow[jq * 4 + 3] = s3;
      mx = fmaxf(mx, fmaxf(fmaxf(s0, s1), fmaxf(s2, s3)));
    }
    float sum = 0.f;
#pragma unroll
    for (int j = 0; j < 56; ++j) {
      float p = expf(srow[j] - mx);
      srow[j] = p;
      sum += p;
    }
    float inv = 1.f / sum;

    float sv[16], sve[16];
#pragma unroll
    for (int c = 0; c < 16; ++c) { sv[c] = 0.f; sve[c] = 0.f; }
#pragma unroll
    for (int jq = 0; jq < 14; ++jq) {
      float p0 = srow[jq * 4], p1 = srow[jq * 4 + 1];
      float p2 = srow[jq * 4 + 2], p3 = srow[jq * 4 + 3];
#pragma unroll
      for (int c = 0; c < 16; ++c) {
        const float* vp  = &vn[c][wl][jq * 4];
        const float* vrp = &vr[c][jq * 4];
        sv[c]  = fmaf(p0, vp[0],  fmaf(p1, vp[1],  fmaf(p2, vp[2],  fmaf(p3, vp[3],  sv[c]))));
        sve[c] = fmaf(p0, vrp[0], fmaf(p1, vrp[1], fmaf(p2, vrp[2], fmaf(p3, vrp[3], sve[c]))));
      }
    }
#pragma unroll
    for (int c = 0; c < 16; ++c) {
      size_t base = (size_t)(g * 16 + c) * NHW + b * HW + i * 56 + w0 + wl;
      sv_ws[base]  = sv[c]  * inv;
      sve_ws[base] = sve[c] * inv;
    }
  }
}

// ---------------------------------------------------------------------------
// K6: per-channel BN stats for sv (blocks 0-127) and sve (blocks 128-255).
// ---------------------------------------------------------------------------
__global__ __launch_bounds__(256) void k6_stats2(
    const float* __restrict__ sv_ws, const float* __restrict__ sve_ws,
    const float* __restrict__ g_sv, const float* __restrict__ b_sv,
    const float* __restrict__ g_sve, const float* __restrict__ b_sve,
    float* __restrict__ bnpar2) {
  const int cb = blockIdx.x;
  const int ch = cb & 127;
  const float* src = (cb < 128) ? sv_ws : sve_ws;
  const float4* p = (const float4*)(src + (size_t)ch * NHW);
  float s = 0.f, s2 = 0.f;
  for (int f = threadIdx.x; f < NHW / 4; f += 256) {
    float4 v = p[f];
    s  += v.x + v.y + v.z + v.w;
    s2 += v.x * v.x + v.y * v.y + v.z * v.z + v.w * v.w;
  }
#pragma unroll
  for (int off = 32; off > 0; off >>= 1) {
    s  += __shfl_down(s, off);
    s2 += __shfl_down(s2, off);
  }
  __shared__ float ls[8];
  int wv_ = threadIdx.x >> 6, ln = threadIdx.x & 63;
  if (ln == 0) { ls[wv_] = s; ls[4 + wv_] = s2; }
  __syncthreads();
  if (threadIdx.x == 0) {
    s  = ls[0] + ls[1] + ls[2] + ls[3];
    s2 = ls[4] + ls[5] + ls[6] + ls[7];
    float m = s / (float)NHW;
    float var = s2 / (float)NHW - m * m;
    float gm = (cb < 128) ? g_sv[ch] : g_sve[ch];
    float bt = (cb < 128) ? b_sv[ch] : b_sve[ch];
    float sc = gm * rsqrtf(var + EPSV);
    int off = (cb < 128) ? 0 : 256;
    bnpar2[off + ch] = sc;
    bnpar2[off + 128 + ch] = bt - m * sc;
  }
}

// ---------------------------------------------------------------------------
// K7: out[b][ch][s] = BN(sv) + BN(sve), float4 elementwise.
// ---------------------------------------------------------------------------
__global__ __launch_bounds__(256) void k7_out(
    const float* __restrict__ sv_ws, const float* __restrict__ sve_ws,
    const float* __restrict__ bnpar2, float* __restrict__ out) {
  int f = blockIdx.x * 256 + threadIdx.x;   // float4 index, 802816 total
  int e = f * 4;
  int bch = e / HW;
  int s = e - bch * HW;
  int b = bch >> 7, ch = bch & 127;
  size_t wsoff = ((size_t)ch * 8 + b) * HW + s;
  float4 a  = *(const float4*)(sv_ws + wsoff);
  float4 c4 = *(const float4*)(sve_ws + wsoff);
  float asc = bnpar2[ch], ash = bnpar2[128 + ch];
  float esc = bnpar2[256 + ch], esh = bnpar2[384 + ch];
  float4 o4;
  o4.x = fmaf(a.x, asc, ash) + fmaf(c4.x, esc, esh);
  o4.y = fmaf(a.y, asc, ash) + fmaf(c4.y, esc, esh);
  o4.z = fmaf(a.z, asc, ash) + fmaf(c4.z, esc, esh);
  o4.w = fmaf(a.w, asc, ash) + fmaf(c4.w, esc, esh);
  *(float4*)(out + (size_t)e) = o4;
}

// ---------------------------------------------------------------------------
extern "C" void kernel_launch(void* const* d_in, const int* in_sizes, int n_in,
                              void* d_out, int out_size, void* d_ws, size_t ws_size,
                              hipStream_t stream) {
  (void)in_sizes; (void)n_in; (void)out_size;

  // Diagnostic guard: if the harness workspace is smaller than our layout,
  // do nothing (deterministic every call -> graph-capture safe). A correct-
  // but-empty run with zero dispatches tells us ws_size is the problem.
  if (ws_size < (size_t)WS_FLOATS * sizeof(float)) return;

  const float* x     = (const float*)d_in[0];
  const float* wq    = (const float*)d_in[1];
  const float* wk    = (const float*)d_in[2];
  const float* wv    = (const float*)d_in[3];
  const float* q_rel = (const float*)d_in[4];
  const float* k_rel = (const float*)d_in[5];
  const float* v_rel = (const float*)d_in[6];
  const float* g_q   = (const float*)d_in[7];
  const float* b_q   = (const float*)d_in[8];
  const float* g_k   = (const float*)d_in[9];
  const float* b_k   = (const float*)d_in[10];
  const float* g_v   = (const float*)d_in[11];
  const float* b_v   = (const float*)d_in[12];
  const float* g_qr  = (const float*)d_in[13];
  const float* b_qr  = (const float*)d_in[14];
  const float* g_kr  = (const float*)d_in[15];
  const float* b_kr  = (const float*)d_in[16];
  const float* g_qk  = (const float*)d_in[17];
  const float* b_qk  = (const float*)d_in[18];
  const float* g_sv  = (const float*)d_in[19];
  const float* b_sv  = (const float*)d_in[20];
  const float* g_sve = (const float*)d_in[21];
  const float* b_sve = (const float*)d_in[22];

  float* ws     = (float*)d_ws;
  float* qkv    = ws + OFF_QKV;
  float* sv_ws  = ws + OFF_SV;
  float* sve_ws = ws + OFF_SVE;
  float* qrb    = ws + OFF_QRB;
  float* krb    = ws + OFF_KRB;
  float* qkvsc  = ws + OFF_QKVSC;
  float* qkvsh  = ws + OFF_QKVSH;
  float* accum  = ws + OFF_ACCUM;
  float* bnpar  = ws + OFF_BNPAR;
  float* bnpar2 = ws + OFF_BNPAR2;

  hipMemsetAsync(accum, 0, 48 * sizeof(float), stream);

  k1_qkv<<<dim3(392, 2), 256, 0, stream>>>(x, wq, wk, wv, qkv);
  k2_stats<<<256, 256, 0, stream>>>(qkv, g_q, b_q, g_k, b_k, g_v, b_v, qkvsc, qkvsh);
  k3_scores<<<dim3(14, 8, 8), 256, 0, stream>>>(qkv, qkvsc, qkvsh, q_rel, k_rel, qrb, krb, accum);
  k4_bn<<<1, 64, 0, stream>>>(accum, g_qr, b_qr, g_kr, b_kr, g_qk, b_qk, bnpar);
  k5_attn<<<dim3(14, 8, 8), 256, 0, stream>>>(qkv, qkvsc, qkvsh, qrb, krb, bnpar, v_rel, sv_ws, sve_ws);
  k6_stats2<<<256, 256, 0, stream>>>(sv_ws, sve_ws, g_sv, b_sv, g_sve, b_sve, bnpar2);
  k7_out<<<3136, 256, 0, stream>>>(sv_ws, sve_ws, bnpar2, (float*)d_out);
}

// Round 5
// 242.532 us; speedup vs baseline: 1.2160x; 1.2160x over previous
//
#include <hip/hip_runtime.h>

#define EPSV 1e-5f

// problem sizes
#define NB   8
#define CC   128
#define HH   56
#define WW   56
#define HW   3136      // 56*56
#define NHW  25088     // 8*3136
#define GG   8

// workspace offsets (in floats) — total 13247584 floats ~= 53 MB
// NOTE: xT (transposed input, [b][c][w][h]) aliases the SV region: it is dead
// once K1 completes, and sv is first written by K5 (after K1 on the stream).
#define OFF_QKV      0            // [256][NHW]  (o-major; spatial = w*56+h)
#define OFF_SV       6422528      // [128][NHW]  (ch-major, ch = g*16+c; spatial w*56+h)
#define OFF_SVE      9633792      // [128][NHW]
#define OFF_QRB      12845056     // [b][g][w][i] = [8][8][56][56]
#define OFF_KRB      13045760     // [b][g][w][j]
#define OFF_QKVSC    13246464     // [256] scale
#define OFF_QKVSH    13246720     // [256] shift
#define OFF_ACCUM    13246976     // [48]: qr_s[8], qr_s2[8], kr_s[8], kr_s2[8], qk_s[8], qk_s2[8]
#define OFF_BNPAR    13247024     // [48]: qr_sc[8], qr_sh[8], kr_sc[8], kr_sh[8], qk_sc[8], qk_sh[8]
#define OFF_BNPAR2   13247072     // [512]: sv_sc[128], sv_sh[128], sve_sc[128], sve_sh[128]
#define WS_FLOATS    13247584

// ---------------------------------------------------------------------------
// K0: transpose x[b][c][h][w] -> xT[b][c][w][h]. One (b,c) plane per block.
// Coalesced float4 on both global sides; LDS pad 60 keeps 16B alignment.
// ---------------------------------------------------------------------------
__global__ __launch_bounds__(256) void k0_transpose(
    const float* __restrict__ x, float* __restrict__ xT) {
  __shared__ float t[56][60];
  const int c = blockIdx.x & 127, b = blockIdx.x >> 7;
  const size_t base = ((size_t)b * 128 + c) * HW;
  const int tid = threadIdx.x;
  for (int f = tid; f < 784; f += 256) {
    int e = f * 4;
    int h = e / 56, w = e - h * 56;          // w multiple of 4
    float4 v = *(const float4*)(x + base + e);
    *(float4*)&t[h][w] = v;
  }
  __syncthreads();
  for (int f = tid; f < 784; f += 256) {
    int e = f * 4;
    int w = e / 56, h0 = e - w * 56;         // h0 multiple of 4
    float4 v = make_float4(t[h0][w], t[h0 + 1][w], t[h0 + 2][w], t[h0 + 3][w]);
    *(float4*)(xT + base + w * 56 + h0) = v;
  }
}

// ---------------------------------------------------------------------------
// K1: QKV 1x1-conv GEMM. out[o][p] = sum_k W[o][k] * xT[b][k][s'], s' = w*56+h.
// Spatial-layout oblivious. C-tile 128o x 64p, 256 threads, 8o x 4p regs each.
// ---------------------------------------------------------------------------
__global__ __launch_bounds__(256) void k1_qkv(
    const float* __restrict__ x, const float* __restrict__ wq,
    const float* __restrict__ wk, const float* __restrict__ wv,
    float* __restrict__ qkv) {
  __shared__ float Wc[32][132];   // [k][o_local], padded row (528B, float4-aligned)
  __shared__ float Xc[32][64];    // [k][p_local]
  const int p0 = blockIdx.x * 64;
  const int o0 = blockIdx.y * 128;
  const int tid = threadIdx.x;
  const int io = tid & 15, ip = tid >> 4;
  const int bb = p0 / HW;
  const int s0 = p0 - bb * HW;    // 64 | 3136, tile never crosses b

  float acc[8][4];
#pragma unroll
  for (int r = 0; r < 8; ++r)
#pragma unroll
    for (int s = 0; s < 4; ++s) acc[r][s] = 0.f;

  for (int kc = 0; kc < 128; kc += 32) {
    if (kc) __syncthreads();
#pragma unroll
    for (int r = 0; r < 4; ++r) {
      int f = tid + 256 * r;            // 1024 float4 slots
      int ol = f >> 3;
      int kq = (f & 7) * 4;
      int o = o0 + ol;
      const float* wsrc = (o < 64) ? (wq + (size_t)o * 128)
                        : (o < 128) ? (wk + (size_t)(o - 64) * 128)
                                    : (wv + (size_t)(o - 128) * 128);
      float4 w4 = *(const float4*)(wsrc + kc + kq);
      Wc[kq + 0][ol] = w4.x; Wc[kq + 1][ol] = w4.y;
      Wc[kq + 2][ol] = w4.z; Wc[kq + 3][ol] = w4.w;
    }
#pragma unroll
    for (int r = 0; r < 2; ++r) {
      int f = tid + 256 * r;            // 512 float4 slots
      int k = f >> 4;
      int pq = (f & 15) * 4;
      float4 x4 = *(const float4*)(x + (size_t)(bb * 128 + kc + k) * HW + s0 + pq);
      *(float4*)&Xc[k][pq] = x4;
    }
    __syncthreads();
#pragma unroll
    for (int k = 0; k < 32; ++k) {
      float4 xv = *(const float4*)&Xc[k][ip * 4];
      float4 wa = *(const float4*)&Wc[k][io * 8];
      float4 wb = *(const float4*)&Wc[k][io * 8 + 4];
      float wr[8] = {wa.x, wa.y, wa.z, wa.w, wb.x, wb.y, wb.z, wb.w};
      float xr[4] = {xv.x, xv.y, xv.z, xv.w};
#pragma unroll
      for (int r = 0; r < 8; ++r)
#pragma unroll
        for (int s = 0; s < 4; ++s)
          acc[r][s] = fmaf(wr[r], xr[s], acc[r][s]);
    }
  }
#pragma unroll
  for (int r = 0; r < 8; ++r) {
    float4 o4 = make_float4(acc[r][0], acc[r][1], acc[r][2], acc[r][3]);
    *(float4*)(qkv + (size_t)(o0 + io * 8 + r) * NHW + p0 + ip * 4) = o4;
  }
}

// ---------------------------------------------------------------------------
// K2: per-channel BN stats for q/k/v -> scale/shift. One block per channel.
// ---------------------------------------------------------------------------
__global__ __launch_bounds__(256) void k2_stats(
    const float* __restrict__ qkv,
    const float* __restrict__ g_q, const float* __restrict__ b_q,
    const float* __restrict__ g_k, const float* __restrict__ b_k,
    const float* __restrict__ g_v, const float* __restrict__ b_v,
    float* __restrict__ sc_out, float* __restrict__ sh_out) {
  const int o = blockIdx.x;
  const float4* p = (const float4*)(qkv + (size_t)o * NHW);
  float s = 0.f, s2 = 0.f;
  for (int f = threadIdx.x; f < NHW / 4; f += 256) {
    float4 v = p[f];
    s  += v.x + v.y + v.z + v.w;
    s2 += v.x * v.x + v.y * v.y + v.z * v.z + v.w * v.w;
  }
#pragma unroll
  for (int off = 32; off > 0; off >>= 1) {
    s  += __shfl_down(s, off);
    s2 += __shfl_down(s2, off);
  }
  __shared__ float ls[8];
  int wv_ = threadIdx.x >> 6, ln = threadIdx.x & 63;
  if (ln == 0) { ls[wv_] = s; ls[4 + wv_] = s2; }
  __syncthreads();
  if (threadIdx.x == 0) {
    s  = ls[0] + ls[1] + ls[2] + ls[3];
    s2 = ls[4] + ls[5] + ls[6] + ls[7];
    float mean = s / (float)NHW;
    float var  = s2 / (float)NHW - mean * mean;
    float g, b;
    if (o < 64)       { g = g_q[o];       b = b_q[o]; }
    else if (o < 128) { g = g_k[o - 64];  b = b_k[o - 64]; }
    else              { g = g_v[o - 128]; b = b_v[o - 128]; }
    float sc = g * rsqrtf(var + EPSV);
    sc_out[o] = sc;
    sh_out[o] = b - mean * sc;
  }
}

// ---------------------------------------------------------------------------
// K3: qr/kr bases (raw, pre-BN) + qk sum/sumsq per group (recomputes S).
// Block = (w-tile, g, b). qkv is [o][b][w][h]: stage reads are contiguous
// 896B runs per (channel, w). qr broadcast along j => stats over N*H*W exact.
// ---------------------------------------------------------------------------
__global__ __launch_bounds__(256) void k3_scores(
    const float* __restrict__ qkv,
    const float* __restrict__ qsc, const float* __restrict__ qsh,
    const float* __restrict__ q_rel, const float* __restrict__ k_rel,
    float* __restrict__ qrb, float* __restrict__ krb,
    float* __restrict__ accum) {
  __shared__ float qn[8][4][56];   // [c][wl][h]
  __shared__ float kn[8][4][56];
  __shared__ float red[4][6];
  const int w0 = blockIdx.x * 4, g = blockIdx.y, b = blockIdx.z;
  const int tid = threadIdx.x;

  // stage: 896 float4 = 2 sides x 8c x 4w x 14 h-quads, all contiguous reads
  for (int f = tid; f < 896; f += 256) {
    int isK = f >= 448;
    int idx = f - 448 * isK;
    int c = idx / 56, r = idx - c * 56;
    int wl = r / 14, hq = (r - wl * 14) * 4;
    int o = g * 8 + c + 64 * isK;
    float4 v = *(const float4*)(qkv + (size_t)o * NHW + b * HW + (w0 + wl) * 56 + hq);
    float sc = qsc[o], sh = qsh[o];
    float4 n = make_float4(fmaf(v.x, sc, sh), fmaf(v.y, sc, sh),
                           fmaf(v.z, sc, sh), fmaf(v.w, sc, sh));
    if (isK) *(float4*)&kn[c][wl][hq] = n;
    else     *(float4*)&qn[c][wl][hq] = n;
  }
  __syncthreads();

  float vqr = 0.f, vqr2 = 0.f, vkr = 0.f, vkr2 = 0.f, vqk = 0.f, vqk2 = 0.f;
  if (tid < 224) {
    const int i = tid % 56, wl = tid / 56;
    float qreg[8];
#pragma unroll
    for (int c = 0; c < 8; ++c) qreg[c] = qn[c][wl][i];
    float qrv = 0.f, krv = 0.f;
#pragma unroll
    for (int c = 0; c < 8; ++c) {
      qrv = fmaf(qreg[c], q_rel[c * 56 + i], qrv);
      krv = fmaf(kn[c][wl][i], k_rel[c * 56 + i], krv);
    }
    size_t bo = ((size_t)(b * 8 + g) * 56 + w0 + wl) * 56 + i;  // [b][g][w][i]
    qrb[bo] = qrv;
    krb[bo] = krv;
    vqr = qrv; vqr2 = qrv * qrv; vkr = krv; vkr2 = krv * krv;
#pragma unroll
    for (int jq = 0; jq < 14; ++jq) {
      float s0 = 0.f, s1 = 0.f, s2 = 0.f, s3 = 0.f;
#pragma unroll
      for (int c = 0; c < 8; ++c) {
        const float* kp = &kn[c][wl][jq * 4];
        float qc = qreg[c];
        s0 = fmaf(qc, kp[0], s0); s1 = fmaf(qc, kp[1], s1);
        s2 = fmaf(qc, kp[2], s2); s3 = fmaf(qc, kp[3], s3);
      }
      vqk  += s0 + s1 + s2 + s3;
      vqk2 += s0 * s0 + s1 * s1 + s2 * s2 + s3 * s3;
    }
  }
  float vals[6] = {vqr, vqr2, vkr, vkr2, vqk, vqk2};
#pragma unroll
  for (int u = 0; u < 6; ++u)
#pragma unroll
    for (int off = 32; off > 0; off >>= 1) vals[u] += __shfl_down(vals[u], off);
  int wv_ = tid >> 6, ln = tid & 63;
  if (ln == 0)
#pragma unroll
    for (int u = 0; u < 6; ++u) red[wv_][u] = vals[u];
  __syncthreads();
  if (tid == 0) {
#pragma unroll
    for (int u = 0; u < 6; ++u)
      atomicAdd(&accum[u * 8 + g], red[0][u] + red[1][u] + red[2][u] + red[3][u]);
  }
}

// ---------------------------------------------------------------------------
// K4: fold accumulated stats into per-group scale/shift for qr, kr, qk.
// ---------------------------------------------------------------------------
__global__ void k4_bn(
    const float* __restrict__ accum,
    const float* __restrict__ g_qr, const float* __restrict__ b_qr,
    const float* __restrict__ g_kr, const float* __restrict__ b_kr,
    const float* __restrict__ g_qk, const float* __restrict__ b_qk,
    float* __restrict__ bnpar) {
  int g = threadIdx.x;
  if (g >= 8) return;
  const float inv1 = 1.f / 25088.f;      // qr/kr count (N*H*W)
  const float inv2 = 1.f / 1404928.f;    // qk count (N*H*H*W)
  float m, v, sc;
  m = accum[g] * inv1;      v = accum[8 + g]  * inv1 - m * m;
  sc = g_qr[g] * rsqrtf(v + EPSV); bnpar[g]      = sc; bnpar[8 + g]  = b_qr[g] - m * sc;
  m = accum[16 + g] * inv1; v = accum[24 + g] * inv1 - m * m;
  sc = g_kr[g] * rsqrtf(v + EPSV); bnpar[16 + g] = sc; bnpar[24 + g] = b_kr[g] - m * sc;
  m = accum[32 + g] * inv2; v = accum[40 + g] * inv2 - m * m;
  sc = g_qk[g] * rsqrtf(v + EPSV); bnpar[32 + g] = sc; bnpar[40 + g] = b_qk[g] - m * sc;
}

// ---------------------------------------------------------------------------
// K5: attention. Block = (w-tile, g, b). Thread (i, wl) owns one softmax row
// in registers. All global reads/writes contiguous ([o][b][w][h] layout).
// Writes raw sv/sve in [ch][b][w][h].
// ---------------------------------------------------------------------------
__global__ __launch_bounds__(256) void k5_attn(
    const float* __restrict__ qkv,
    const float* __restrict__ qsc, const float* __restrict__ qsh,
    const float* __restrict__ qrb, const float* __restrict__ krb,
    const float* __restrict__ bnpar, const float* __restrict__ v_rel,
    float* __restrict__ sv_ws, float* __restrict__ sve_ws) {
  __shared__ float qn[8][4][56];    // [c][wl][h]
  __shared__ float kn[8][4][56];
  __shared__ float vn[16][4][56];
  __shared__ float qrn[4][56];
  __shared__ float krn[4][56];
  __shared__ float vr[16][56];
  const int w0 = blockIdx.x * 4, g = blockIdx.y, b = blockIdx.z;
  const int tid = threadIdx.x;

  // stage: 1792 float4 = (8q + 8k + 16v) x 4w x 14 h-quads, contiguous reads
  for (int f = tid; f < 1792; f += 256) {
    int c, o; float* dst;
    int idx = f;
    if (f < 448)      { c = idx / 56;                      o = g * 8 + c;         dst = (float*)qn + c * 224; }
    else if (f < 896) { idx = f - 448; c = idx / 56;       o = 64 + g * 8 + c;    dst = (float*)kn + c * 224; }
    else              { idx = f - 896; c = idx / 56;       o = 128 + g * 16 + c;  dst = (float*)vn + c * 224; }
    int r = idx - c * 56;
    int wl = r / 14, hq = (r - wl * 14) * 4;
    float4 v = *(const float4*)(qkv + (size_t)o * NHW + b * HW + (w0 + wl) * 56 + hq);
    float sc = qsc[o], sh = qsh[o];
    float4 n = make_float4(fmaf(v.x, sc, sh), fmaf(v.y, sc, sh),
                           fmaf(v.z, sc, sh), fmaf(v.w, sc, sh));
    *(float4*)(dst + wl * 56 + hq) = n;
  }
  {
    float qr_sc = bnpar[g],      qr_sh = bnpar[8 + g];
    float kr_sc = bnpar[16 + g], kr_sh = bnpar[24 + g];
    if (tid < 224) {
      int i = tid % 56, wl = tid / 56;
      size_t bo = ((size_t)(b * 8 + g) * 56 + w0 + wl) * 56 + i;  // [b][g][w][i]
      qrn[wl][i] = fmaf(qrb[bo], qr_sc, qr_sh);
      krn[wl][i] = fmaf(krb[bo], kr_sc, kr_sh);
    }
  }
  for (int f = tid; f < 896; f += 256) ((float*)vr)[f] = v_rel[f];
  __syncthreads();

  if (tid < 224) {
    const int i = tid % 56, wl = tid / 56;
    float qreg[8];
#pragma unroll
    for (int c = 0; c < 8; ++c) qreg[c] = qn[c][wl][i];
    const float qksc = bnpar[32 + g];
    const float addi = bnpar[40 + g] + qrn[wl][i];

    float srow[56];
    float mx = -3.402823466e38f;
#pragma unroll
    for (int jq = 0; jq < 14; ++jq) {
      float s0 = 0.f, s1 = 0.f, s2 = 0.f, s3 = 0.f;
#pragma unroll
      for (int c = 0; c < 8; ++c) {
        const float* kp = &kn[c][wl][jq * 4];
        float qc = qreg[c];
        s0 = fmaf(qc, kp[0], s0); s1 = fmaf(qc, kp[1], s1);
        s2 = fmaf(qc, kp[2], s2); s3 = fmaf(qc, kp[3], s3);
      }
      const float* krp = &krn[wl][jq * 4];
      s0 = fmaf(qksc, s0, addi + krp[0]);
      s1 = fmaf(qksc, s1, addi + krp[1]);
      s2 = fmaf(qksc, s2, addi + krp[2]);
      s3 = fmaf(qksc, s3, addi + krp[3]);
      srow[jq * 4 + 0] = s0; srow[jq * 4 + 1] = s1;
      srow[jq * 4 + 2] = s2; srow[jq * 4 + 3] = s3;
      mx = fmaxf(mx, fmaxf(fmaxf(s0, s1), fmaxf(s2, s3)));
    }
    float sum = 0.f;
#pragma unroll
    for (int j = 0; j < 56; ++j) {
      float p = expf(srow[j] - mx);
      srow[j] = p;
      sum += p;
    }
    float inv = 1.f / sum;

    float sv[16], sve[16];
#pragma unroll
    for (int c = 0; c < 16; ++c) { sv[c] = 0.f; sve[c] = 0.f; }
#pragma unroll
    for (int jq = 0; jq < 14; ++jq) {
      float p0 = srow[jq * 4], p1 = srow[jq * 4 + 1];
      float p2 = srow[jq * 4 + 2], p3 = srow[jq * 4 + 3];
#pragma unroll
      for (int c = 0; c < 16; ++c) {
        const float* vp  = &vn[c][wl][jq * 4];
        const float* vrp = &vr[c][jq * 4];
        sv[c]  = fmaf(p0, vp[0],  fmaf(p1, vp[1],  fmaf(p2, vp[2],  fmaf(p3, vp[3],  sv[c]))));
        sve[c] = fmaf(p0, vrp[0], fmaf(p1, vrp[1], fmaf(p2, vrp[2], fmaf(p3, vrp[3], sve[c]))));
      }
    }
#pragma unroll
    for (int c = 0; c < 16; ++c) {
      size_t base = (size_t)(g * 16 + c) * NHW + b * HW + (w0 + wl) * 56 + i;
      sv_ws[base]  = sv[c]  * inv;   // contiguous across consecutive tid (i)
      sve_ws[base] = sve[c] * inv;
    }
  }
}

// ---------------------------------------------------------------------------
// K6: per-channel BN stats for sv (blocks 0-127) and sve (blocks 128-255).
// ---------------------------------------------------------------------------
__global__ __launch_bounds__(256) void k6_stats2(
    const float* __restrict__ sv_ws, const float* __restrict__ sve_ws,
    const float* __restrict__ g_sv, const float* __restrict__ b_sv,
    const float* __restrict__ g_sve, const float* __restrict__ b_sve,
    float* __restrict__ bnpar2) {
  const int cb = blockIdx.x;
  const int ch = cb & 127;
  const float* src = (cb < 128) ? sv_ws : sve_ws;
  const float4* p = (const float4*)(src + (size_t)ch * NHW);
  float s = 0.f, s2 = 0.f;
  for (int f = threadIdx.x; f < NHW / 4; f += 256) {
    float4 v = p[f];
    s  += v.x + v.y + v.z + v.w;
    s2 += v.x * v.x + v.y * v.y + v.z * v.z + v.w * v.w;
  }
#pragma unroll
  for (int off = 32; off > 0; off >>= 1) {
    s  += __shfl_down(s, off);
    s2 += __shfl_down(s2, off);
  }
  __shared__ float ls[8];
  int wv_ = threadIdx.x >> 6, ln = threadIdx.x & 63;
  if (ln == 0) { ls[wv_] = s; ls[4 + wv_] = s2; }
  __syncthreads();
  if (threadIdx.x == 0) {
    s  = ls[0] + ls[1] + ls[2] + ls[3];
    s2 = ls[4] + ls[5] + ls[6] + ls[7];
    float m = s / (float)NHW;
    float var = s2 / (float)NHW - m * m;
    float gm = (cb < 128) ? g_sv[ch] : g_sve[ch];
    float bt = (cb < 128) ? b_sv[ch] : b_sve[ch];
    float sc = gm * rsqrtf(var + EPSV);
    int off = (cb < 128) ? 0 : 256;
    bnpar2[off + ch] = sc;
    bnpar2[off + 128 + ch] = bt - m * sc;
  }
}

// ---------------------------------------------------------------------------
// K7: fused double-BN + transpose back: out[b][ch][h][w] from
// sv/sve[ch][b][w][h]. One (ch,b) plane per block, LDS-tiled.
// ---------------------------------------------------------------------------
__global__ __launch_bounds__(256) void k7_out(
    const float* __restrict__ sv_ws, const float* __restrict__ sve_ws,
    const float* __restrict__ bnpar2, float* __restrict__ out) {
  __shared__ float t[56][60];
  const int ch = blockIdx.x & 127, b = blockIdx.x >> 7;
  const int tid = threadIdx.x;
  const float asc = bnpar2[ch], ash = bnpar2[128 + ch];
  const float esc = bnpar2[256 + ch], esh = bnpar2[384 + ch];
  const size_t pin = ((size_t)ch * NB + b) * HW;
  for (int f = tid; f < 784; f += 256) {
    int e = f * 4;
    int w = e / 56, h = e - w * 56;          // h multiple of 4
    float4 a  = *(const float4*)(sv_ws + pin + e);
    float4 c4 = *(const float4*)(sve_ws + pin + e);
    float4 o4;
    o4.x = fmaf(a.x, asc, ash) + fmaf(c4.x, esc, esh);
    o4.y = fmaf(a.y, asc, ash) + fmaf(c4.y, esc, esh);
    o4.z = fmaf(a.z, asc, ash) + fmaf(c4.z, esc, esh);
    o4.w = fmaf(a.w, asc, ash) + fmaf(c4.w, esc, esh);
    *(float4*)&t[w][h] = o4;
  }
  __syncthreads();
  const size_t pout = ((size_t)b * 128 + ch) * HW;
  for (int f = tid; f < 784; f += 256) {
    int e = f * 4;
    int h = e / 56, w0 = e - h * 56;         // w0 multiple of 4
    float4 o4 = make_float4(t[w0][h], t[w0 + 1][h], t[w0 + 2][h], t[w0 + 3][h]);
    *(float4*)(out + pout + h * 56 + w0) = o4;
  }
}

// ---------------------------------------------------------------------------
extern "C" void kernel_launch(void* const* d_in, const int* in_sizes, int n_in,
                              void* d_out, int out_size, void* d_ws, size_t ws_size,
                              hipStream_t stream) {
  (void)in_sizes; (void)n_in; (void)out_size;
  if (ws_size < (size_t)WS_FLOATS * sizeof(float)) return;  // diagnostic guard

  const float* x     = (const float*)d_in[0];
  const float* wq    = (const float*)d_in[1];
  const float* wk    = (const float*)d_in[2];
  const float* wv    = (const float*)d_in[3];
  const float* q_rel = (const float*)d_in[4];
  const float* k_rel = (const float*)d_in[5];
  const float* v_rel = (const float*)d_in[6];
  const float* g_q   = (const float*)d_in[7];
  const float* b_q   = (const float*)d_in[8];
  const float* g_k   = (const float*)d_in[9];
  const float* b_k   = (const float*)d_in[10];
  const float* g_v   = (const float*)d_in[11];
  const float* b_v   = (const float*)d_in[12];
  const float* g_qr  = (const float*)d_in[13];
  const float* b_qr  = (const float*)d_in[14];
  const float* g_kr  = (const float*)d_in[15];
  const float* b_kr  = (const float*)d_in[16];
  const float* g_qk  = (const float*)d_in[17];
  const float* b_qk  = (const float*)d_in[18];
  const float* g_sv  = (const float*)d_in[19];
  const float* b_sv  = (const float*)d_in[20];
  const float* g_sve = (const float*)d_in[21];
  const float* b_sve = (const float*)d_in[22];

  float* ws     = (float*)d_ws;
  float* qkv    = ws + OFF_QKV;
  float* sv_ws  = ws + OFF_SV;
  float* sve_ws = ws + OFF_SVE;
  float* xT     = ws + OFF_SV;      // aliases SV region (dead after K1)
  float* qrb    = ws + OFF_QRB;
  float* krb    = ws + OFF_KRB;
  float* qkvsc  = ws + OFF_QKVSC;
  float* qkvsh  = ws + OFF_QKVSH;
  float* accum  = ws + OFF_ACCUM;
  float* bnpar  = ws + OFF_BNPAR;
  float* bnpar2 = ws + OFF_BNPAR2;

  hipMemsetAsync(accum, 0, 48 * sizeof(float), stream);

  k0_transpose<<<1024, 256, 0, stream>>>(x, xT);
  k1_qkv<<<dim3(392, 2), 256, 0, stream>>>(xT, wq, wk, wv, qkv);
  k2_stats<<<256, 256, 0, stream>>>(qkv, g_q, b_q, g_k, b_k, g_v, b_v, qkvsc, qkvsh);
  k3_scores<<<dim3(14, 8, 8), 256, 0, stream>>>(qkv, qkvsc, qkvsh, q_rel, k_rel, qrb, krb, accum);
  k4_bn<<<1, 64, 0, stream>>>(accum, g_qr, b_qr, g_kr, b_kr, g_qk, b_qk, bnpar);
  k5_attn<<<dim3(14, 8, 8), 256, 0, stream>>>(qkv, qkvsc, qkvsh, qrb, krb, bnpar, v_rel, sv_ws, sve_ws);
  k6_stats2<<<256, 256, 0, stream>>>(sv_ws, sve_ws, g_sv, b_sv, g_sve, b_sve, bnpar2);
  k7_out<<<1024, 256, 0, stream>>>(sv_ws, sve_ws, bnpar2, (float*)d_out);
}

// Round 6
// 213.263 us; speedup vs baseline: 1.3828x; 1.1372x over previous
//
#include <hip/hip_runtime.h>

#define EPSV 1e-5f

// problem sizes
#define NB   8
#define CC   128
#define HH   56
#define WW   56
#define HW   3136      // 56*56
#define NHW  25088     // 8*3136
#define GG   8

// workspace offsets (in floats) — total 13247584 floats ~= 53 MB
// xT ([b][c][w][h]) aliases SV region (dead after K1; sv first written by K5).
// Padded atomic accum (48 slots x 32 floats = 6KB) aliases SVE region head
// (accum lifetime memset->K4; sve lifetime K5->K7; disjoint. xT ends exactly
// at OFF_SVE so no overlap with accum either).
#define OFF_QKV      0            // [256][NHW]  (o-major; spatial = w*56+h)
#define OFF_SV       6422528      // [128][NHW]  (ch-major, ch = g*16+c; spatial w*56+h)
#define OFF_SVE      9633792      // [128][NHW]
#define OFF_QRB      12845056     // [b][g][w][i] = [8][8][56][56]
#define OFF_KRB      13045760     // [b][g][w][j]
#define OFF_QKVSC    13246464     // [256] scale
#define OFF_QKVSH    13246720     // [256] shift
#define OFF_BNPAR    13247024     // [48]: qr_sc[8], qr_sh[8], kr_sc[8], kr_sh[8], qk_sc[8], qk_sh[8]
#define OFF_BNPAR2   13247072     // [512]: sv_sc[128], sv_sh[128], sve_sc[128], sve_sh[128]
#define WS_FLOATS    13247584

// padded accumulator slot: one 128B cache line per (u,g) counter
#define ACC_IDX(u, g) (((u) * 8 + (g)) * 32)

// ---------------------------------------------------------------------------
// K0: transpose x[b][c][h][w] -> xT[b][c][w][h]. One (b,c) plane per block.
// ---------------------------------------------------------------------------
__global__ __launch_bounds__(256) void k0_transpose(
    const float* __restrict__ x, float* __restrict__ xT) {
  __shared__ float t[56][60];
  const int c = blockIdx.x & 127, b = blockIdx.x >> 7;
  const size_t base = ((size_t)b * 128 + c) * HW;
  const int tid = threadIdx.x;
  for (int f = tid; f < 784; f += 256) {
    int e = f * 4;
    int h = e / 56, w = e - h * 56;          // w multiple of 4
    float4 v = *(const float4*)(x + base + e);
    *(float4*)&t[h][w] = v;
  }
  __syncthreads();
  for (int f = tid; f < 784; f += 256) {
    int e = f * 4;
    int w = e / 56, h0 = e - w * 56;         // h0 multiple of 4
    float4 v = make_float4(t[h0][w], t[h0 + 1][w], t[h0 + 2][w], t[h0 + 3][w]);
    *(float4*)(xT + base + w * 56 + h0) = v;
  }
}

// ---------------------------------------------------------------------------
// K1: QKV 1x1-conv GEMM. out[o][p] = sum_k W[o][k] * xT[b][k][s'], s' = w*56+h.
// ---------------------------------------------------------------------------
__global__ __launch_bounds__(256) void k1_qkv(
    const float* __restrict__ x, const float* __restrict__ wq,
    const float* __restrict__ wk, const float* __restrict__ wv,
    float* __restrict__ qkv) {
  __shared__ float Wc[32][132];   // [k][o_local], padded row (528B, float4-aligned)
  __shared__ float Xc[32][64];    // [k][p_local]
  const int p0 = blockIdx.x * 64;
  const int o0 = blockIdx.y * 128;
  const int tid = threadIdx.x;
  const int io = tid & 15, ip = tid >> 4;
  const int bb = p0 / HW;
  const int s0 = p0 - bb * HW;    // 64 | 3136, tile never crosses b

  float acc[8][4];
#pragma unroll
  for (int r = 0; r < 8; ++r)
#pragma unroll
    for (int s = 0; s < 4; ++s) acc[r][s] = 0.f;

  for (int kc = 0; kc < 128; kc += 32) {
    if (kc) __syncthreads();
#pragma unroll
    for (int r = 0; r < 4; ++r) {
      int f = tid + 256 * r;            // 1024 float4 slots
      int ol = f >> 3;
      int kq = (f & 7) * 4;
      int o = o0 + ol;
      const float* wsrc = (o < 64) ? (wq + (size_t)o * 128)
                        : (o < 128) ? (wk + (size_t)(o - 64) * 128)
                                    : (wv + (size_t)(o - 128) * 128);
      float4 w4 = *(const float4*)(wsrc + kc + kq);
      Wc[kq + 0][ol] = w4.x; Wc[kq + 1][ol] = w4.y;
      Wc[kq + 2][ol] = w4.z; Wc[kq + 3][ol] = w4.w;
    }
#pragma unroll
    for (int r = 0; r < 2; ++r) {
      int f = tid + 256 * r;            // 512 float4 slots
      int k = f >> 4;
      int pq = (f & 15) * 4;
      float4 x4 = *(const float4*)(x + (size_t)(bb * 128 + kc + k) * HW + s0 + pq);
      *(float4*)&Xc[k][pq] = x4;
    }
    __syncthreads();
#pragma unroll
    for (int k = 0; k < 32; ++k) {
      float4 xv = *(const float4*)&Xc[k][ip * 4];
      float4 wa = *(const float4*)&Wc[k][io * 8];
      float4 wb = *(const float4*)&Wc[k][io * 8 + 4];
      float wr[8] = {wa.x, wa.y, wa.z, wa.w, wb.x, wb.y, wb.z, wb.w};
      float xr[4] = {xv.x, xv.y, xv.z, xv.w};
#pragma unroll
      for (int r = 0; r < 8; ++r)
#pragma unroll
        for (int s = 0; s < 4; ++s)
          acc[r][s] = fmaf(wr[r], xr[s], acc[r][s]);
    }
  }
#pragma unroll
  for (int r = 0; r < 8; ++r) {
    float4 o4 = make_float4(acc[r][0], acc[r][1], acc[r][2], acc[r][3]);
    *(float4*)(qkv + (size_t)(o0 + io * 8 + r) * NHW + p0 + ip * 4) = o4;
  }
}

// ---------------------------------------------------------------------------
// K2: per-channel BN stats for q/k/v -> scale/shift. One block per channel.
// ---------------------------------------------------------------------------
__global__ __launch_bounds__(256) void k2_stats(
    const float* __restrict__ qkv,
    const float* __restrict__ g_q, const float* __restrict__ b_q,
    const float* __restrict__ g_k, const float* __restrict__ b_k,
    const float* __restrict__ g_v, const float* __restrict__ b_v,
    float* __restrict__ sc_out, float* __restrict__ sh_out) {
  const int o = blockIdx.x;
  const float4* p = (const float4*)(qkv + (size_t)o * NHW);
  float s = 0.f, s2 = 0.f;
  for (int f = threadIdx.x; f < NHW / 4; f += 256) {
    float4 v = p[f];
    s  += v.x + v.y + v.z + v.w;
    s2 += v.x * v.x + v.y * v.y + v.z * v.z + v.w * v.w;
  }
#pragma unroll
  for (int off = 32; off > 0; off >>= 1) {
    s  += __shfl_down(s, off);
    s2 += __shfl_down(s2, off);
  }
  __shared__ float ls[8];
  int wv_ = threadIdx.x >> 6, ln = threadIdx.x & 63;
  if (ln == 0) { ls[wv_] = s; ls[4 + wv_] = s2; }
  __syncthreads();
  if (threadIdx.x == 0) {
    s  = ls[0] + ls[1] + ls[2] + ls[3];
    s2 = ls[4] + ls[5] + ls[6] + ls[7];
    float mean = s / (float)NHW;
    float var  = s2 / (float)NHW - mean * mean;
    float g, b;
    if (o < 64)       { g = g_q[o];       b = b_q[o]; }
    else if (o < 128) { g = g_k[o - 64];  b = b_k[o - 64]; }
    else              { g = g_v[o - 128]; b = b_v[o - 128]; }
    float sc = g * rsqrtf(var + EPSV);
    sc_out[o] = sc;
    sh_out[o] = b - mean * sc;
  }
}

// ---------------------------------------------------------------------------
// K3: qr/kr bases (raw, pre-BN) + qk sum/sumsq per group (recomputes S).
// Atomics now land on one 128B line per (u,g) counter (48 independent lines).
// ---------------------------------------------------------------------------
__global__ __launch_bounds__(256) void k3_scores(
    const float* __restrict__ qkv,
    const float* __restrict__ qsc, const float* __restrict__ qsh,
    const float* __restrict__ q_rel, const float* __restrict__ k_rel,
    float* __restrict__ qrb, float* __restrict__ krb,
    float* __restrict__ accum) {
  __shared__ float qn[8][4][56];   // [c][wl][h]
  __shared__ float kn[8][4][56];
  __shared__ float red[4][6];
  const int w0 = blockIdx.x * 4, g = blockIdx.y, b = blockIdx.z;
  const int tid = threadIdx.x;

  for (int f = tid; f < 896; f += 256) {
    int isK = f >= 448;
    int idx = f - 448 * isK;
    int c = idx / 56, r = idx - c * 56;
    int wl = r / 14, hq = (r - wl * 14) * 4;
    int o = g * 8 + c + 64 * isK;
    float4 v = *(const float4*)(qkv + (size_t)o * NHW + b * HW + (w0 + wl) * 56 + hq);
    float sc = qsc[o], sh = qsh[o];
    float4 n = make_float4(fmaf(v.x, sc, sh), fmaf(v.y, sc, sh),
                           fmaf(v.z, sc, sh), fmaf(v.w, sc, sh));
    if (isK) *(float4*)&kn[c][wl][hq] = n;
    else     *(float4*)&qn[c][wl][hq] = n;
  }
  __syncthreads();

  float vqr = 0.f, vqr2 = 0.f, vkr = 0.f, vkr2 = 0.f, vqk = 0.f, vqk2 = 0.f;
  if (tid < 224) {
    const int i = tid % 56, wl = tid / 56;
    float qreg[8];
#pragma unroll
    for (int c = 0; c < 8; ++c) qreg[c] = qn[c][wl][i];
    float qrv = 0.f, krv = 0.f;
#pragma unroll
    for (int c = 0; c < 8; ++c) {
      qrv = fmaf(qreg[c], q_rel[c * 56 + i], qrv);
      krv = fmaf(kn[c][wl][i], k_rel[c * 56 + i], krv);
    }
    size_t bo = ((size_t)(b * 8 + g) * 56 + w0 + wl) * 56 + i;  // [b][g][w][i]
    qrb[bo] = qrv;
    krb[bo] = krv;
    vqr = qrv; vqr2 = qrv * qrv; vkr = krv; vkr2 = krv * krv;
#pragma unroll
    for (int jq = 0; jq < 14; ++jq) {
      float s0 = 0.f, s1 = 0.f, s2 = 0.f, s3 = 0.f;
#pragma unroll
      for (int c = 0; c < 8; ++c) {
        const float* kp = &kn[c][wl][jq * 4];
        float qc = qreg[c];
        s0 = fmaf(qc, kp[0], s0); s1 = fmaf(qc, kp[1], s1);
        s2 = fmaf(qc, kp[2], s2); s3 = fmaf(qc, kp[3], s3);
      }
      vqk  += s0 + s1 + s2 + s3;
      vqk2 += s0 * s0 + s1 * s1 + s2 * s2 + s3 * s3;
    }
  }
  float vals[6] = {vqr, vqr2, vkr, vkr2, vqk, vqk2};
#pragma unroll
  for (int u = 0; u < 6; ++u)
#pragma unroll
    for (int off = 32; off > 0; off >>= 1) vals[u] += __shfl_down(vals[u], off);
  int wv_ = tid >> 6, ln = tid & 63;
  if (ln == 0)
#pragma unroll
    for (int u = 0; u < 6; ++u) red[wv_][u] = vals[u];
  __syncthreads();
  if (tid == 0) {
#pragma unroll
    for (int u = 0; u < 6; ++u)
      atomicAdd(&accum[ACC_IDX(u, g)], red[0][u] + red[1][u] + red[2][u] + red[3][u]);
  }
}

// ---------------------------------------------------------------------------
// K4: fold accumulated stats into per-group scale/shift for qr, kr, qk.
// ---------------------------------------------------------------------------
__global__ void k4_bn(
    const float* __restrict__ accum,
    const float* __restrict__ g_qr, const float* __restrict__ b_qr,
    const float* __restrict__ g_kr, const float* __restrict__ b_kr,
    const float* __restrict__ g_qk, const float* __restrict__ b_qk,
    float* __restrict__ bnpar) {
  int g = threadIdx.x;
  if (g >= 8) return;
  const float inv1 = 1.f / 25088.f;      // qr/kr count (N*H*W)
  const float inv2 = 1.f / 1404928.f;    // qk count (N*H*H*W)
  float m, v, sc;
  m = accum[ACC_IDX(0, g)] * inv1; v = accum[ACC_IDX(1, g)] * inv1 - m * m;
  sc = g_qr[g] * rsqrtf(v + EPSV); bnpar[g]      = sc; bnpar[8 + g]  = b_qr[g] - m * sc;
  m = accum[ACC_IDX(2, g)] * inv1; v = accum[ACC_IDX(3, g)] * inv1 - m * m;
  sc = g_kr[g] * rsqrtf(v + EPSV); bnpar[16 + g] = sc; bnpar[24 + g] = b_kr[g] - m * sc;
  m = accum[ACC_IDX(4, g)] * inv2; v = accum[ACC_IDX(5, g)] * inv2 - m * m;
  sc = g_qk[g] * rsqrtf(v + EPSV); bnpar[32 + g] = sc; bnpar[40 + g] = b_qk[g] - m * sc;
}

// ---------------------------------------------------------------------------
// K5: attention. Block = (w-tile, g, b). Thread (i, wl) owns one softmax row
// in registers. All global reads/writes contiguous ([o][b][w][h] layout).
// ---------------------------------------------------------------------------
__global__ __launch_bounds__(256) void k5_attn(
    const float* __restrict__ qkv,
    const float* __restrict__ qsc, const float* __restrict__ qsh,
    const float* __restrict__ qrb, const float* __restrict__ krb,
    const float* __restrict__ bnpar, const float* __restrict__ v_rel,
    float* __restrict__ sv_ws, float* __restrict__ sve_ws) {
  __shared__ float qn[8][4][56];    // [c][wl][h]
  __shared__ float kn[8][4][56];
  __shared__ float vn[16][4][56];
  __shared__ float qrn[4][56];
  __shared__ float krn[4][56];
  __shared__ float vr[16][56];
  const int w0 = blockIdx.x * 4, g = blockIdx.y, b = blockIdx.z;
  const int tid = threadIdx.x;

  for (int f = tid; f < 1792; f += 256) {
    int c, o; float* dst;
    int idx = f;
    if (f < 448)      { c = idx / 56;                      o = g * 8 + c;         dst = (float*)qn + c * 224; }
    else if (f < 896) { idx = f - 448; c = idx / 56;       o = 64 + g * 8 + c;    dst = (float*)kn + c * 224; }
    else              { idx = f - 896; c = idx / 56;       o = 128 + g * 16 + c;  dst = (float*)vn + c * 224; }
    int r = idx - c * 56;
    int wl = r / 14, hq = (r - wl * 14) * 4;
    float4 v = *(const float4*)(qkv + (size_t)o * NHW + b * HW + (w0 + wl) * 56 + hq);
    float sc = qsc[o], sh = qsh[o];
    float4 n = make_float4(fmaf(v.x, sc, sh), fmaf(v.y, sc, sh),
                           fmaf(v.z, sc, sh), fmaf(v.w, sc, sh));
    *(float4*)(dst + wl * 56 + hq) = n;
  }
  {
    float qr_sc = bnpar[g],      qr_sh = bnpar[8 + g];
    float kr_sc = bnpar[16 + g], kr_sh = bnpar[24 + g];
    if (tid < 224) {
      int i = tid % 56, wl = tid / 56;
      size_t bo = ((size_t)(b * 8 + g) * 56 + w0 + wl) * 56 + i;  // [b][g][w][i]
      qrn[wl][i] = fmaf(qrb[bo], qr_sc, qr_sh);
      krn[wl][i] = fmaf(krb[bo], kr_sc, kr_sh);
    }
  }
  for (int f = tid; f < 896; f += 256) ((float*)vr)[f] = v_rel[f];
  __syncthreads();

  if (tid < 224) {
    const int i = tid % 56, wl = tid / 56;
    float qreg[8];
#pragma unroll
    for (int c = 0; c < 8; ++c) qreg[c] = qn[c][wl][i];
    const float qksc = bnpar[32 + g];
    const float addi = bnpar[40 + g] + qrn[wl][i];

    float srow[56];
    float mx = -3.402823466e38f;
#pragma unroll
    for (int jq = 0; jq < 14; ++jq) {
      float s0 = 0.f, s1 = 0.f, s2 = 0.f, s3 = 0.f;
#pragma unroll
      for (int c = 0; c < 8; ++c) {
        const float* kp = &kn[c][wl][jq * 4];
        float qc = qreg[c];
        s0 = fmaf(qc, kp[0], s0); s1 = fmaf(qc, kp[1], s1);
        s2 = fmaf(qc, kp[2], s2); s3 = fmaf(qc, kp[3], s3);
      }
      const float* krp = &krn[wl][jq * 4];
      s0 = fmaf(qksc, s0, addi + krp[0]);
      s1 = fmaf(qksc, s1, addi + krp[1]);
      s2 = fmaf(qksc, s2, addi + krp[2]);
      s3 = fmaf(qksc, s3, addi + krp[3]);
      srow[jq * 4 + 0] = s0; srow[jq * 4 + 1] = s1;
      srow[jq * 4 + 2] = s2; srow[jq * 4 + 3] = s3;
      mx = fmaxf(mx, fmaxf(fmaxf(s0, s1), fmaxf(s2, s3)));
    }
    float sum = 0.f;
#pragma unroll
    for (int j = 0; j < 56; ++j) {
      float p = expf(srow[j] - mx);
      srow[j] = p;
      sum += p;
    }
    float inv = 1.f / sum;

    float sv[16], sve[16];
#pragma unroll
    for (int c = 0; c < 16; ++c) { sv[c] = 0.f; sve[c] = 0.f; }
#pragma unroll
    for (int jq = 0; jq < 14; ++jq) {
      float p0 = srow[jq * 4], p1 = srow[jq * 4 + 1];
      float p2 = srow[jq * 4 + 2], p3 = srow[jq * 4 + 3];
#pragma unroll
      for (int c = 0; c < 16; ++c) {
        const float* vp  = &vn[c][wl][jq * 4];
        const float* vrp = &vr[c][jq * 4];
        sv[c]  = fmaf(p0, vp[0],  fmaf(p1, vp[1],  fmaf(p2, vp[2],  fmaf(p3, vp[3],  sv[c]))));
        sve[c] = fmaf(p0, vrp[0], fmaf(p1, vrp[1], fmaf(p2, vrp[2], fmaf(p3, vrp[3], sve[c]))));
      }
    }
#pragma unroll
    for (int c = 0; c < 16; ++c) {
      size_t base = (size_t)(g * 16 + c) * NHW + b * HW + (w0 + wl) * 56 + i;
      sv_ws[base]  = sv[c]  * inv;   // contiguous across consecutive tid (i)
      sve_ws[base] = sve[c] * inv;
    }
  }
}

// ---------------------------------------------------------------------------
// K6: per-channel BN stats for sv (blocks 0-127) and sve (blocks 128-255).
// ---------------------------------------------------------------------------
__global__ __launch_bounds__(256) void k6_stats2(
    const float* __restrict__ sv_ws, const float* __restrict__ sve_ws,
    const float* __restrict__ g_sv, const float* __restrict__ b_sv,
    const float* __restrict__ g_sve, const float* __restrict__ b_sve,
    float* __restrict__ bnpar2) {
  const int cb = blockIdx.x;
  const int ch = cb & 127;
  const float* src = (cb < 128) ? sv_ws : sve_ws;
  const float4* p = (const float4*)(src + (size_t)ch * NHW);
  float s = 0.f, s2 = 0.f;
  for (int f = threadIdx.x; f < NHW / 4; f += 256) {
    float4 v = p[f];
    s  += v.x + v.y + v.z + v.w;
    s2 += v.x * v.x + v.y * v.y + v.z * v.z + v.w * v.w;
  }
#pragma unroll
  for (int off = 32; off > 0; off >>= 1) {
    s  += __shfl_down(s, off);
    s2 += __shfl_down(s2, off);
  }
  __shared__ float ls[8];
  int wv_ = threadIdx.x >> 6, ln = threadIdx.x & 63;
  if (ln == 0) { ls[wv_] = s; ls[4 + wv_] = s2; }
  __syncthreads();
  if (threadIdx.x == 0) {
    s  = ls[0] + ls[1] + ls[2] + ls[3];
    s2 = ls[4] + ls[5] + ls[6] + ls[7];
    float m = s / (float)NHW;
    float var = s2 / (float)NHW - m * m;
    float gm = (cb < 128) ? g_sv[ch] : g_sve[ch];
    float bt = (cb < 128) ? b_sv[ch] : b_sve[ch];
    float sc = gm * rsqrtf(var + EPSV);
    int off = (cb < 128) ? 0 : 256;
    bnpar2[off + ch] = sc;
    bnpar2[off + 128 + ch] = bt - m * sc;
  }
}

// ---------------------------------------------------------------------------
// K7: fused double-BN + transpose back: out[b][ch][h][w] from
// sv/sve[ch][b][w][h]. One (ch,b) plane per block, LDS-tiled.
// ---------------------------------------------------------------------------
__global__ __launch_bounds__(256) void k7_out(
    const float* __restrict__ sv_ws, const float* __restrict__ sve_ws,
    const float* __restrict__ bnpar2, float* __restrict__ out) {
  __shared__ float t[56][60];
  const int ch = blockIdx.x & 127, b = blockIdx.x >> 7;
  const int tid = threadIdx.x;
  const float asc = bnpar2[ch], ash = bnpar2[128 + ch];
  const float esc = bnpar2[256 + ch], esh = bnpar2[384 + ch];
  const size_t pin = ((size_t)ch * NB + b) * HW;
  for (int f = tid; f < 784; f += 256) {
    int e = f * 4;
    int w = e / 56, h = e - w * 56;          // h multiple of 4
    float4 a  = *(const float4*)(sv_ws + pin + e);
    float4 c4 = *(const float4*)(sve_ws + pin + e);
    float4 o4;
    o4.x = fmaf(a.x, asc, ash) + fmaf(c4.x, esc, esh);
    o4.y = fmaf(a.y, asc, ash) + fmaf(c4.y, esc, esh);
    o4.z = fmaf(a.z, asc, ash) + fmaf(c4.z, esc, esh);
    o4.w = fmaf(a.w, asc, ash) + fmaf(c4.w, esc, esh);
    *(float4*)&t[w][h] = o4;
  }
  __syncthreads();
  const size_t pout = ((size_t)b * 128 + ch) * HW;
  for (int f = tid; f < 784; f += 256) {
    int e = f * 4;
    int h = e / 56, w0 = e - h * 56;         // w0 multiple of 4
    float4 o4 = make_float4(t[w0][h], t[w0 + 1][h], t[w0 + 2][h], t[w0 + 3][h]);
    *(float4*)(out + pout + h * 56 + w0) = o4;
  }
}

// ---------------------------------------------------------------------------
extern "C" void kernel_launch(void* const* d_in, const int* in_sizes, int n_in,
                              void* d_out, int out_size, void* d_ws, size_t ws_size,
                              hipStream_t stream) {
  (void)in_sizes; (void)n_in; (void)out_size;
  if (ws_size < (size_t)WS_FLOATS * sizeof(float)) return;  // diagnostic guard

  const float* x     = (const float*)d_in[0];
  const float* wq    = (const float*)d_in[1];
  const float* wk    = (const float*)d_in[2];
  const float* wv    = (const float*)d_in[3];
  const float* q_rel = (const float*)d_in[4];
  const float* k_rel = (const float*)d_in[5];
  const float* v_rel = (const float*)d_in[6];
  const float* g_q   = (const float*)d_in[7];
  const float* b_q   = (const float*)d_in[8];
  const float* g_k   = (const float*)d_in[9];
  const float* b_k   = (const float*)d_in[10];
  const float* g_v   = (const float*)d_in[11];
  const float* b_v   = (const float*)d_in[12];
  const float* g_qr  = (const float*)d_in[13];
  const float* b_qr  = (const float*)d_in[14];
  const float* g_kr  = (const float*)d_in[15];
  const float* b_kr  = (const float*)d_in[16];
  const float* g_qk  = (const float*)d_in[17];
  const float* b_qk  = (const float*)d_in[18];
  const float* g_sv  = (const float*)d_in[19];
  const float* b_sv  = (const float*)d_in[20];
  const float* g_sve = (const float*)d_in[21];
  const float* b_sve = (const float*)d_in[22];

  float* ws     = (float*)d_ws;
  float* qkv    = ws + OFF_QKV;
  float* sv_ws  = ws + OFF_SV;
  float* sve_ws = ws + OFF_SVE;
  float* xT     = ws + OFF_SV;      // aliases SV region (dead after K1)
  float* accum  = ws + OFF_SVE;     // padded 48x32 floats; aliases SVE head (dead before K5)
  float* qrb    = ws + OFF_QRB;
  float* krb    = ws + OFF_KRB;
  float* qkvsc  = ws + OFF_QKVSC;
  float* qkvsh  = ws + OFF_QKVSH;
  float* bnpar  = ws + OFF_BNPAR;
  float* bnpar2 = ws + OFF_BNPAR2;

  hipMemsetAsync(accum, 0, 48 * 32 * sizeof(float), stream);

  k0_transpose<<<1024, 256, 0, stream>>>(x, xT);
  k1_qkv<<<dim3(392, 2), 256, 0, stream>>>(xT, wq, wk, wv, qkv);
  k2_stats<<<256, 256, 0, stream>>>(qkv, g_q, b_q, g_k, b_k, g_v, b_v, qkvsc, qkvsh);
  k3_scores<<<dim3(14, 8, 8), 256, 0, stream>>>(qkv, qkvsc, qkvsh, q_rel, k_rel, qrb, krb, accum);
  k4_bn<<<1, 64, 0, stream>>>(accum, g_qr, b_qr, g_kr, b_kr, g_qk, b_qk, bnpar);
  k5_attn<<<dim3(14, 8, 8), 256, 0, stream>>>(qkv, qkvsc, qkvsh, qrb, krb, bnpar, v_rel, sv_ws, sve_ws);
  k6_stats2<<<256, 256, 0, stream>>>(sv_ws, sve_ws, g_sv, b_sv, g_sve, b_sve, bnpar2);
  k7_out<<<1024, 256, 0, stream>>>(sv_ws, sve_ws, bnpar2, (float*)d_out);
}